// Round 9
// baseline (154.401 us; speedup 1.0000x reference)
//
#include <hip/hip_runtime.h>
#include <math.h>

#define DIM 512
#define NP  64
#define RPB 128            // rows per block (8 waves x 16 rows)
#define TAU 4e-5f          // gap34 flag threshold (cosine units, covers bf16-split err)
#define LISTCAP 8192
#define RFB 128

// workspace layout (bytes)
#define WS_PTW   0          // float[512][64] raw transposed protos      (131072)
#define WS_BHI   131072     // ushort frag-linear hi [16][4][64][8]      (65536)
#define WS_BLO   196608     // ushort frag-linear lo                     (65536)
#define WS_INV64 262144     // double[64]                                (512)
#define WS_CNT   262656     // int (+pad)                                (128)
#define WS_LIST  262784     // int[LISTCAP]                              (32768)

typedef __attribute__((ext_vector_type(8))) short bf16x8;
typedef __attribute__((ext_vector_type(4))) float f32x4;

__device__ __forceinline__ unsigned short f2bf(float f) {   // RNE fp32->bf16
  const unsigned int u = __float_as_uint(f);
  return (unsigned short)((u + 0x7FFFu + ((u >> 16) & 1u)) >> 16);
}
__device__ __forceinline__ float bf2f(unsigned short h) {
  return __uint_as_float(((unsigned int)h) << 16);
}

__device__ __forceinline__ void ins4f(float v, int idx, float& v0, float& v1,
                                      float& v2, float& v3, int& j0, int& j1,
                                      int& j2, int& j3) {
  const bool b0 = v > v0, b1 = v > v1, b2 = v > v2, b3 = v > v3;
  v3 = b2 ? v2 : (b3 ? v : v3);  j3 = b2 ? j2 : (b3 ? idx : j3);
  v2 = b1 ? v1 : (b2 ? v : v2);  j2 = b1 ? j1 : (b2 ? idx : j2);
  v1 = b0 ? v0 : (b1 ? v : v1);  j1 = b0 ? j0 : (b1 ? idx : j1);
  v0 = b0 ? v  : v0;             j0 = b0 ? idx : j0;
}

__device__ __forceinline__ void ins3d(double v, int idx, double& b0, double& b1,
                                      double& b2, int& k0, int& k1, int& k2) {
  const bool c0 = v > b0, c1 = v > b1, c2 = v > b2;
  b2 = c1 ? b1 : (c2 ? v : b2);  k2 = c1 ? k1 : (c2 ? idx : k2);
  b1 = c0 ? b0 : (c1 ? v : b1);  k1 = c0 ? k0 : (c1 ? idx : k1);
  b0 = c0 ? v  : b0;             k0 = c0 ? idx : k0;
}

// ---------------------------------------------------------------------------
// Kernel 1: transpose protos -> ptw[k][p] (raw); fp64 inverse norms; zero cnt.
// One wave per prototype.
// ---------------------------------------------------------------------------
__global__ __launch_bounds__(256) void prep_kernel(
    const float* __restrict__ protos, float* __restrict__ ptw,
    double* __restrict__ inv64, int* __restrict__ cnt) {
  if (blockIdx.x == 0 && threadIdx.x == 0) *cnt = 0;
  const int p = (blockIdx.x * 256 + threadIdx.x) >> 6;
  const int lane = threadIdx.x & 63;
  if (p >= NP) return;
  const float4* pr = (const float4*)(protos + (size_t)p * DIM);
  const float4 a = pr[lane * 2];
  const float4 b = pr[lane * 2 + 1];
  double ss = (double)a.x * a.x + (double)a.y * a.y + (double)a.z * a.z +
              (double)a.w * a.w + (double)b.x * b.x + (double)b.y * b.y +
              (double)b.z * b.z + (double)b.w * b.w;
#pragma unroll
  for (int m = 1; m < 64; m <<= 1) ss += __shfl_xor(ss, m);
  const double inv = 1.0 / fmax(sqrt(ss), 1e-12);
  if (lane == 0) inv64[p] = inv;
  const float v[8] = {a.x, a.y, a.z, a.w, b.x, b.y, b.z, b.w};
#pragma unroll
  for (int e = 0; e < 8; ++e)
    ptw[(size_t)(lane * 8 + e) * NP + p] = v[e];
}

// ---------------------------------------------------------------------------
// Kernel 2: build B fragments (bf16 hi/lo split) straight from protos.
// Fragment (ks,pt,lane,e) = p_hat[pt*16+(lane&15)][ks*32+(lane>>4)*8+e].
// ---------------------------------------------------------------------------
__global__ __launch_bounds__(64) void prep_frag_kernel(
    const float* __restrict__ protos, const double* __restrict__ inv64,
    unsigned short* __restrict__ bhi, unsigned short* __restrict__ blo) {
  const int ks = blockIdx.x >> 2;
  const int pt = blockIdx.x & 3;
  const int l = threadIdx.x;
  const int p = pt * 16 + (l & 15);
  const int k0 = ks * 32 + (l >> 4) * 8;
  const double inv = inv64[p];
  const size_t base = ((size_t)(ks * 4 + pt) * 64 + l) * 8;
#pragma unroll
  for (int e = 0; e < 8; ++e) {
    const float v = (float)((double)protos[(size_t)p * DIM + k0 + e] * inv);
    const unsigned short h = f2bf(v);
    bhi[base + e] = h;
    blo[base + e] = f2bf(v - bf2f(h));
  }
}

// ---------------------------------------------------------------------------
// Kernel 3: MFMA sim (split-bf16, 3 passes) -> top4 -> softmax -> gather.
// 512 threads = 8 waves, 128 rows/block, grid 512 (2 blocks/CU, 4 waves/SIMD).
// B-hi (64 KiB) staged to LDS ONCE per block; ONE barrier total.
// A: depth-3 register prefetch (HBM). B-lo: depth-2 (L1/L2-hot).
// ---------------------------------------------------------------------------
__global__ __launch_bounds__(512, 4) void sim_kernel(
    const float* __restrict__ query, const float* __restrict__ protos,
    const unsigned short* __restrict__ bhi_u, const unsigned short* __restrict__ blo_u,
    float* __restrict__ out, int* __restrict__ cnt, int* __restrict__ list) {
  __shared__ __align__(16) short BHI[16 * 4 * 64 * 8];   // 64 KiB frag-linear
  __shared__ float4 wiS[8][16];

  const int t = threadIdx.x;
  const int wid = t >> 6;
  const int l = t & 63;
  const int lr = l & 15;          // A row / D col (proto) spatial index
  const int lg = l >> 4;          // k-group; D row group
  const int wr0 = blockIdx.x * RPB + wid * 16;

  // ---- stage BHI once: 8 passes x 512 threads x 16 B (coalesced) ----
  {
    const float4* gs = (const float4*)bhi_u;
    float4 tmp[8];
#pragma unroll
    for (int i = 0; i < 8; ++i) tmp[i] = gs[i * 512 + t];
#pragma unroll
    for (int i = 0; i < 8; ++i)
      *(float4*)&BHI[(i * 512 + t) * 8] = tmp[i];
  }
  __syncthreads();

  const float* aq = query + (size_t)(wr0 + lr) * DIM + lg * 8;
  const bf16x8* blp = (const bf16x8*)blo_u;

  f32x4 acc[4] = {};
  float ss = 0.f;

  float4 abuf[3][2];              // A triple-buffer (HBM stream)
  bf16x8 lbuf[2][4];              // B-lo double-buffer (cache-hot)

#pragma unroll
  for (int s = 0; s < 3; ++s) {
    abuf[s][0] = *(const float4*)(aq + s * 32);
    abuf[s][1] = *(const float4*)(aq + s * 32 + 4);
  }
#pragma unroll
  for (int s = 0; s < 2; ++s)
#pragma unroll
    for (int j = 0; j < 4; ++j)
      lbuf[s][j] = blp[(size_t)(s * 4 + j) * 64 + l];

#pragma unroll
  for (int ks = 0; ks < 16; ++ks) {
    const int ab = ks % 3;
    const int bb = ks & 1;
    // split A into hi/lo bf16 fragments; fold in row sumsq
    bf16x8 ahi, alo;
    {
      const float4 a0 = abuf[ab][0];
      const float4 a1 = abuf[ab][1];
      const float av[8] = {a0.x, a0.y, a0.z, a0.w, a1.x, a1.y, a1.z, a1.w};
#pragma unroll
      for (int i = 0; i < 8; ++i) {
        const unsigned short h = f2bf(av[i]);
        ahi[i] = (short)h;
        alo[i] = (short)f2bf(av[i] - bf2f(h));
        ss += av[i] * av[i];
      }
    }
    // refill A buffer for step ks+3
    if (ks + 3 < 16) {
      abuf[ab][0] = *(const float4*)(aq + (ks + 3) * 32);
      abuf[ab][1] = *(const float4*)(aq + (ks + 3) * 32 + 4);
    }
    // B-hi from LDS (conflict-free linear b128)
    bf16x8 bh[4];
#pragma unroll
    for (int pt = 0; pt < 4; ++pt)
      bh[pt] = *(const bf16x8*)&BHI[((ks * 4 + pt) * 64 + l) * 8];
    // 12 MFMAs: acc[pt] += Ahi*Bhi + Ahi*Blo + Alo*Bhi
#pragma unroll
    for (int pt = 0; pt < 4; ++pt) {
      acc[pt] = __builtin_amdgcn_mfma_f32_16x16x32_bf16(ahi, bh[pt],       acc[pt], 0, 0, 0);
      acc[pt] = __builtin_amdgcn_mfma_f32_16x16x32_bf16(ahi, lbuf[bb][pt], acc[pt], 0, 0, 0);
      acc[pt] = __builtin_amdgcn_mfma_f32_16x16x32_bf16(alo, bh[pt],       acc[pt], 0, 0, 0);
    }
    // refill B-lo buffer for step ks+2
    if (ks + 2 < 16) {
#pragma unroll
      for (int j = 0; j < 4; ++j)
        lbuf[bb][j] = blp[(size_t)((ks + 2) * 4 + j) * 64 + l];
    }
  }

  // full sumsq of row lr (combine the 4 k-groups)
  ss += __shfl_xor(ss, 16);
  ss += __shfl_xor(ss, 32);

  // ---- selection: D layout col(proto)=lr, row=lg*4+e ----
#pragma unroll
  for (int e = 0; e < 4; ++e) {
    float v0 = -1e30f, v1 = -1e30f, v2 = -1e30f, v3 = -1e30f;
    int j0 = 0, j1 = 0, j2 = 0, j3 = 0;
#pragma unroll
    for (int pt = 0; pt < 4; ++pt)
      ins4f(acc[pt][e], pt * 16 + lr, v0, v1, v2, v3, j0, j1, j2, j3);
#pragma unroll
    for (int m = 1; m <= 8; m <<= 1) {   // butterfly within 16-lane group
      const float p0 = __shfl_xor(v0, m), p1 = __shfl_xor(v1, m);
      const float p2 = __shfl_xor(v2, m), p3 = __shfl_xor(v3, m);
      const int q0 = __shfl_xor(j0, m), q1 = __shfl_xor(j1, m);
      const int q2 = __shfl_xor(j2, m), q3 = __shfl_xor(j3, m);
      ins4f(p0, q0, v0, v1, v2, v3, j0, j1, j2, j3);
      ins4f(p1, q1, v0, v1, v2, v3, j0, j1, j2, j3);
      ins4f(p2, q2, v0, v1, v2, v3, j0, j1, j2, j3);
      ins4f(p3, q3, v0, v1, v2, v3, j0, j1, j2, j3);
    }
    const float ssr = __shfl(ss, lg * 4 + e);   // row (lg*4+e) sumsq
    if (lr == e) {                              // writer lane 16*lg + e
      const int row = lg * 4 + e;
      const float qi = 1.0f / fmaxf(sqrtf(ssr), 1e-12f);
      const float s0 = v0 * qi, s1 = v1 * qi, s2 = v2 * qi, s3 = v3 * qi;
      const float e1 = expf(s1 - s0), e2 = expf(s2 - s0);
      const float inv = 1.0f / (1.0f + e1 + e2);
      wiS[wid][row] = make_float4(inv, e1 * inv, e2 * inv,
                                  __int_as_float(j0 | (j1 << 6) | (j2 << 12)));
      if (s2 - s3 < TAU) {
        const int pos = atomicAdd(cnt, 1);
        if (pos < LISTCAP) list[pos] = wr0 + row;
      }
    }
  }

  // ---- epilogue: weighted gather, coalesced 1 KB accesses ----
#pragma unroll 2
  for (int r = 0; r < 16; ++r) {
    const float4 wi = wiS[wid][r];
    const int pack = __float_as_int(wi.w);
    const int i0 = pack & 63, i1 = (pack >> 6) & 63, i2 = (pack >> 12) & 63;
    const float* p0 = protos + (size_t)i0 * DIM;
    const float* p1 = protos + (size_t)i1 * DIM;
    const float* p2 = protos + (size_t)i2 * DIM;
    float* orow = out + (size_t)(wr0 + r) * DIM;
#pragma unroll
    for (int h = 0; h < 2; ++h) {
      const int col = h * 256 + l * 4;
      const float4 x = *(const float4*)(p0 + col);
      const float4 y = *(const float4*)(p1 + col);
      const float4 z = *(const float4*)(p2 + col);
      float4 res;
      res.x = wi.x * x.x + wi.y * y.x + wi.z * z.x;
      res.y = wi.x * x.y + wi.y * y.y + wi.z * z.y;
      res.z = wi.x * x.z + wi.y * y.z + wi.z * z.z;
      res.w = wi.x * x.w + wi.y * y.w + wi.z * z.w;
      *(float4*)(orow + col) = res;
    }
  }
}

// ---------------------------------------------------------------------------
// Kernel 4: fp64 refine of compacted near-tie rows. One wave per row.
// ---------------------------------------------------------------------------
__global__ __launch_bounds__(256) void refine_kernel(
    const float* __restrict__ query, const float* __restrict__ protos,
    const float* __restrict__ ptw, const double* __restrict__ inv64,
    const int* __restrict__ cnt, const int* __restrict__ list,
    float* __restrict__ out) {
  const int n = min(*cnt, LISTCAP);
  const int lane = threadIdx.x & 63;
  const int gw = blockIdx.x * 4 + (threadIdx.x >> 6);

  for (int i = gw; i < n; i += RFB * 4) {
    const int row = list[i];
    const float* q = query + (size_t)row * DIM;
    double a0 = 0.0, a1 = 0.0, a2 = 0.0, a3 = 0.0;
    float qs = 0.f;
#pragma unroll 4
    for (int k = 0; k < DIM; k += 4) {
      const float4 qv = *(const float4*)(q + k);
      a0 = fma((double)qv.x, (double)ptw[(size_t)(k + 0) * NP + lane], a0);
      a1 = fma((double)qv.y, (double)ptw[(size_t)(k + 1) * NP + lane], a1);
      a2 = fma((double)qv.z, (double)ptw[(size_t)(k + 2) * NP + lane], a2);
      a3 = fma((double)qv.w, (double)ptw[(size_t)(k + 3) * NP + lane], a3);
      qs += qv.x * qv.x + qv.y * qv.y + qv.z * qv.z + qv.w * qv.w;
    }
    const double sim = (a0 + a1 + a2 + a3) * inv64[lane];

    double b0 = sim, b1 = -1e300, b2 = -1e300;
    int k0 = lane, k1 = 0, k2 = 0;
#pragma unroll
    for (int m = 1; m <= 32; m <<= 1) {
      const double p0 = __shfl_xor(b0, m), p1 = __shfl_xor(b1, m),
                   p2 = __shfl_xor(b2, m);
      const int q0 = __shfl_xor(k0, m), q1 = __shfl_xor(k1, m),
                q2 = __shfl_xor(k2, m);
      ins3d(p0, q0, b0, b1, b2, k0, k1, k2);
      ins3d(p1, q1, b0, b1, b2, k0, k1, k2);
      ins3d(p2, q2, b0, b1, b2, k0, k1, k2);
    }
    const double qi = 1.0 / fmax(sqrt((double)qs), 1e-12);
    const double s0 = b0 * qi, s1 = b1 * qi, s2 = b2 * qi;
    const double e1 = exp(s1 - s0), e2 = exp(s2 - s0);
    const double inv = 1.0 / (1.0 + e1 + e2);
    const double w0 = inv, w1 = e1 * inv, w2 = e2 * inv;
    const float* p0r = protos + (size_t)k0 * DIM;
    const float* p1r = protos + (size_t)k1 * DIM;
    const float* p2r = protos + (size_t)k2 * DIM;
#pragma unroll
    for (int u = 0; u < 2; ++u) {
      const int col = u * 256 + lane * 4;
      const float4 x = *(const float4*)(p0r + col);
      const float4 y = *(const float4*)(p1r + col);
      const float4 z = *(const float4*)(p2r + col);
      float4 res;
      res.x = (float)(w0 * x.x + w1 * y.x + w2 * z.x);
      res.y = (float)(w0 * x.y + w1 * y.y + w2 * z.y);
      res.z = (float)(w0 * x.z + w1 * y.z + w2 * z.z);
      res.w = (float)(w0 * x.w + w1 * y.w + w2 * z.w);
      *(float4*)(out + (size_t)row * DIM + col) = res;
    }
  }
}

extern "C" void kernel_launch(void* const* d_in, const int* in_sizes, int n_in,
                              void* d_out, int out_size, void* d_ws, size_t ws_size,
                              hipStream_t stream) {
  const float* query = (const float*)d_in[0];
  const float* protos = (const float*)d_in[1];
  float* out = (float*)d_out;
  float* ptw = (float*)((char*)d_ws + WS_PTW);
  unsigned short* bhi = (unsigned short*)((char*)d_ws + WS_BHI);
  unsigned short* blo = (unsigned short*)((char*)d_ws + WS_BLO);
  double* inv64 = (double*)((char*)d_ws + WS_INV64);
  int* cnt = (int*)((char*)d_ws + WS_CNT);
  int* list = (int*)((char*)d_ws + WS_LIST);

  const int nrows = in_sizes[0] / DIM;

  hipLaunchKernelGGL(prep_kernel, dim3(16), dim3(256), 0, stream,
                     protos, ptw, inv64, cnt);
  hipLaunchKernelGGL(prep_frag_kernel, dim3(64), dim3(64), 0, stream,
                     protos, inv64, bhi, blo);
  hipLaunchKernelGGL(sim_kernel, dim3(nrows / RPB), dim3(512), 0, stream,
                     query, protos, bhi, blo, out, cnt, list);
  hipLaunchKernelGGL(refine_kernel, dim3(RFB), dim3(256), 0, stream,
                     query, protos, ptw, inv64, cnt, list, out);
}

// Round 11
// 109.921 us; speedup vs baseline: 1.4047x; 1.4047x over previous
//
#include <hip/hip_runtime.h>
#include <math.h>

#define DIM 512
#define NP  64
#define RPB 64             // rows per block (4 waves x 16)
#define BK  64             // floats per staged k-chunk (256 B/row)
#define NCH 8              // chunks (512/64)
#define TAU 4e-5f          // gap34 flag threshold (cosine units)
#define LISTCAP 8192
#define RFB 128

// workspace layout (bytes)
#define WS_PTW   0          // float[512][64] raw transposed protos   (131072)
#define WS_BHI   131072     // ushort frag-linear hi [16][4][64][8]   (65536)
#define WS_BLO   196608     // ushort frag-linear lo                  (65536)
#define WS_INV64 262144     // double[64]                             (512)
#define WS_CNT   262656     // int (+pad)                             (128)
#define WS_LIST  262784     // int[LISTCAP]                           (32768)

typedef __attribute__((ext_vector_type(8))) short bf16x8;
typedef __attribute__((ext_vector_type(4))) float f32x4;

__device__ __forceinline__ unsigned short f2bf(float f) {   // RNE fp32->bf16
  const unsigned int u = __float_as_uint(f);
  return (unsigned short)((u + 0x7FFFu + ((u >> 16) & 1u)) >> 16);
}
__device__ __forceinline__ float bf2f(unsigned short h) {
  return __uint_as_float(((unsigned int)h) << 16);
}

__device__ __forceinline__ void gload_lds16(const void* g, void* l) {
  __builtin_amdgcn_global_load_lds(
      (const __attribute__((address_space(1))) void*)g,
      (__attribute__((address_space(3))) void*)l, 16, 0, 0);
}

__device__ __forceinline__ void ins4f(float v, int idx, float& v0, float& v1,
                                      float& v2, float& v3, int& j0, int& j1,
                                      int& j2, int& j3) {
  const bool b0 = v > v0, b1 = v > v1, b2 = v > v2, b3 = v > v3;
  v3 = b2 ? v2 : (b3 ? v : v3);  j3 = b2 ? j2 : (b3 ? idx : j3);
  v2 = b1 ? v1 : (b2 ? v : v2);  j2 = b1 ? j1 : (b2 ? idx : j2);
  v1 = b0 ? v0 : (b1 ? v : v1);  j1 = b0 ? j0 : (b1 ? idx : j1);
  v0 = b0 ? v  : v0;             j0 = b0 ? idx : j0;
}

__device__ __forceinline__ void ins3d(double v, int idx, double& b0, double& b1,
                                      double& b2, int& k0, int& k1, int& k2) {
  const bool c0 = v > b0, c1 = v > b1, c2 = v > b2;
  b2 = c1 ? b1 : (c2 ? v : b2);  k2 = c1 ? k1 : (c2 ? idx : k2);
  b1 = c0 ? b0 : (c1 ? v : b1);  k1 = c0 ? k0 : (c1 ? idx : k1);
  b0 = c0 ? v  : b0;             k0 = c0 ? idx : k0;
}

// ---------------------------------------------------------------------------
// Kernel 1: transpose protos -> ptw[k][p]; fp64 inverse norms; zero cnt.
// ---------------------------------------------------------------------------
__global__ __launch_bounds__(256) void prep_kernel(
    const float* __restrict__ protos, float* __restrict__ ptw,
    double* __restrict__ inv64, int* __restrict__ cnt) {
  if (blockIdx.x == 0 && threadIdx.x == 0) *cnt = 0;
  const int p = (blockIdx.x * 256 + threadIdx.x) >> 6;
  const int lane = threadIdx.x & 63;
  if (p >= NP) return;
  const float4* pr = (const float4*)(protos + (size_t)p * DIM);
  const float4 a = pr[lane * 2];
  const float4 b = pr[lane * 2 + 1];
  double ss = (double)a.x * a.x + (double)a.y * a.y + (double)a.z * a.z +
              (double)a.w * a.w + (double)b.x * b.x + (double)b.y * b.y +
              (double)b.z * b.z + (double)b.w * b.w;
#pragma unroll
  for (int m = 1; m < 64; m <<= 1) ss += __shfl_xor(ss, m);
  const double inv = 1.0 / fmax(sqrt(ss), 1e-12);
  if (lane == 0) inv64[p] = inv;
  const float v[8] = {a.x, a.y, a.z, a.w, b.x, b.y, b.z, b.w};
#pragma unroll
  for (int e = 0; e < 8; ++e)
    ptw[(size_t)(lane * 8 + e) * NP + p] = v[e];
}

// ---------------------------------------------------------------------------
// Kernel 2: build B fragments (bf16 hi/lo split) from protos.
// Fragment (ks,pt,lane,e) = p_hat[pt*16+(lane&15)][ks*32+(lane>>4)*8+e].
// ---------------------------------------------------------------------------
__global__ __launch_bounds__(64) void prep_frag_kernel(
    const float* __restrict__ protos, const double* __restrict__ inv64,
    unsigned short* __restrict__ bhi, unsigned short* __restrict__ blo) {
  const int ks = blockIdx.x >> 2;
  const int pt = blockIdx.x & 3;
  const int l = threadIdx.x;
  const int p = pt * 16 + (l & 15);
  const int k0 = ks * 32 + (l >> 4) * 8;
  const double inv = inv64[p];
  const size_t base = ((size_t)(ks * 4 + pt) * 64 + l) * 8;
#pragma unroll
  for (int e = 0; e < 8; ++e) {
    const float v = (float)((double)protos[(size_t)p * DIM + k0 + e] * inv);
    const unsigned short h = f2bf(v);
    bhi[base + e] = h;
    blo[base + e] = f2bf(v - bf2f(h));
  }
}

// ---------------------------------------------------------------------------
// Kernel 3: MFMA sim (split-bf16, 3 passes) -> top4 -> softmax -> gather.
// 256 thr = 4 waves, 64 rows/block, grid 1024.
// A: global_load_lds width-16 staging, contiguous 1KB/instr, double-buffered,
//    1 barrier/chunk; XOR-swizzle (row&7)<<4 applied on the GLOBAL source,
//    linear LDS dest, swizzled ds_read_b128 (conflict-free).
// B: depth-2 static register prefetch of hi/lo frags (contiguous, L2-hot).
// ---------------------------------------------------------------------------
__global__ __launch_bounds__(256) void sim_kernel(
    const float* __restrict__ query, const float* __restrict__ protos,
    const unsigned short* __restrict__ bhi_u, const unsigned short* __restrict__ blo_u,
    float* __restrict__ out, int* __restrict__ cnt, int* __restrict__ list) {
  __shared__ __align__(16) float Abuf[2][RPB * BK];   // 2 x 16 KiB [row][k]
  __shared__ float4 wiS[4][16];

  const int t = threadIdx.x;
  const int wid = t >> 6;
  const int l = t & 63;
  const int lr = l & 15;          // A row / D col (proto) spatial index
  const int lg = l >> 4;          // k-group; D row group
  const int row0 = blockIdx.x * RPB;
  const int wr0 = row0 + wid * 16;

  // staging geometry: instr i of this wave covers rows wid*16+i*4 .. +3
  const int srow_i = l >> 4;            // row offset within instr (0..3)
  const int sbyte = (l & 15) * 16;      // byte col within 256B chunk segment

  auto stage = [&](int bufi, int cc) {
#pragma unroll
    for (int i = 0; i < 4; ++i) {
      const int r0 = wid * 16 + i * 4;            // wave-uniform
      const int row = r0 + srow_i;
      const char* src = (const char*)query +
          ((size_t)(row0 + row) * DIM + cc * BK) * 4 +
          (sbyte ^ ((row & 7) << 4));
      gload_lds16(src, &Abuf[bufi][r0 * BK]);
    }
  };

  const bf16x8* bhp = (const bf16x8*)bhi_u;
  const bf16x8* blp = (const bf16x8*)blo_u;

  f32x4 acc[4] = {};
  float ss = 0.f;

  bf16x8 hbuf[2][4], lbuf[2][4];       // B frags for steps ks, ks+1
#pragma unroll
  for (int s = 0; s < 2; ++s)
#pragma unroll
    for (int j = 0; j < 4; ++j) {
      hbuf[s][j] = bhp[(size_t)(s * 4 + j) * 64 + l];
      lbuf[s][j] = blp[(size_t)(s * 4 + j) * 64 + l];
    }

  stage(0, 0);
  __syncthreads();                      // chunk 0 landed

  const int swz = (lr & 7) << 4;

  for (int c = 0; c < NCH; ++c) {
    const int cur = c & 1;
    if (c + 1 < NCH) stage(cur ^ 1, c + 1);   // issue next chunk early

    const char* ab = (const char*)&Abuf[cur][0];
#pragma unroll
    for (int s = 0; s < 2; ++s) {             // two MFMA k-steps per chunk
      const int ks = c * 2 + s;               // bb = ks&1 == s (c*2 even)
      const int rbase = (wid * 16 + lr) * 256 + s * 128;   // FIX: +wid*16
      const float4 a0 = *(const float4*)(ab + rbase + ((lg * 32) ^ swz));
      const float4 a1 = *(const float4*)(ab + rbase + ((lg * 32 + 16) ^ swz));
      bf16x8 ahi, alo;
      const float av[8] = {a0.x, a0.y, a0.z, a0.w, a1.x, a1.y, a1.z, a1.w};
#pragma unroll
      for (int i = 0; i < 8; ++i) {
        const unsigned int u = __float_as_uint(av[i]);
        const unsigned short h = (unsigned short)(u >> 16);   // trunc split
        ahi[i] = (short)h;
        alo[i] = (short)f2bf(av[i] - bf2f(h));
        ss += av[i] * av[i];
      }
#pragma unroll
      for (int pt = 0; pt < 4; ++pt) {
        acc[pt] = __builtin_amdgcn_mfma_f32_16x16x32_bf16(ahi, hbuf[s][pt], acc[pt], 0, 0, 0);
        acc[pt] = __builtin_amdgcn_mfma_f32_16x16x32_bf16(ahi, lbuf[s][pt], acc[pt], 0, 0, 0);
        acc[pt] = __builtin_amdgcn_mfma_f32_16x16x32_bf16(alo, hbuf[s][pt], acc[pt], 0, 0, 0);
      }
      if (ks + 2 < 16) {                      // refill slot s for step ks+2
#pragma unroll
        for (int j = 0; j < 4; ++j) {
          hbuf[s][j] = bhp[(size_t)((ks + 2) * 4 + j) * 64 + l];
          lbuf[s][j] = blp[(size_t)((ks + 2) * 4 + j) * 64 + l];
        }
      }
    }
    __syncthreads();                    // next chunk landed; LDS reuse safe
  }

  // full sumsq of row (wid*16+lr): combine the 4 k-groups
  ss += __shfl_xor(ss, 16);
  ss += __shfl_xor(ss, 32);

  // ---- selection: D layout col(proto)=lr, row=lg*4+e ----
#pragma unroll
  for (int e = 0; e < 4; ++e) {
    float v0 = -1e30f, v1 = -1e30f, v2 = -1e30f, v3 = -1e30f;
    int j0 = 0, j1 = 0, j2 = 0, j3 = 0;
#pragma unroll
    for (int pt = 0; pt < 4; ++pt)
      ins4f(acc[pt][e], pt * 16 + lr, v0, v1, v2, v3, j0, j1, j2, j3);
#pragma unroll
    for (int m = 1; m <= 8; m <<= 1) {   // butterfly within 16-lane group
      const float p0 = __shfl_xor(v0, m), p1 = __shfl_xor(v1, m);
      const float p2 = __shfl_xor(v2, m), p3 = __shfl_xor(v3, m);
      const int q0 = __shfl_xor(j0, m), q1 = __shfl_xor(j1, m);
      const int q2 = __shfl_xor(j2, m), q3 = __shfl_xor(j3, m);
      ins4f(p0, q0, v0, v1, v2, v3, j0, j1, j2, j3);
      ins4f(p1, q1, v0, v1, v2, v3, j0, j1, j2, j3);
      ins4f(p2, q2, v0, v1, v2, v3, j0, j1, j2, j3);
      ins4f(p3, q3, v0, v1, v2, v3, j0, j1, j2, j3);
    }
    const float ssr = __shfl(ss, lg * 4 + e);   // row (lg*4+e) sumsq
    if (lr == e) {                              // writer lane 16*lg + e
      const int row = lg * 4 + e;
      const float qi = 1.0f / fmaxf(sqrtf(ssr), 1e-12f);
      const float s0 = v0 * qi, s1 = v1 * qi, s2 = v2 * qi, s3 = v3 * qi;
      const float e1 = expf(s1 - s0), e2 = expf(s2 - s0);
      const float inv = 1.0f / (1.0f + e1 + e2);
      wiS[wid][row] = make_float4(inv, e1 * inv, e2 * inv,
                                  __int_as_float(j0 | (j1 << 6) | (j2 << 12)));
      if (s2 - s3 < TAU) {
        const int pos = atomicAdd(cnt, 1);
        if (pos < LISTCAP) list[pos] = wr0 + row;
      }
    }
  }

  // ---- epilogue: weighted gather, coalesced 1 KB accesses ----
#pragma unroll 2
  for (int r = 0; r < 16; ++r) {
    const float4 wi = wiS[wid][r];
    const int pack = __float_as_int(wi.w);
    const int i0 = pack & 63, i1 = (pack >> 6) & 63, i2 = (pack >> 12) & 63;
    const float* p0 = protos + (size_t)i0 * DIM;
    const float* p1 = protos + (size_t)i1 * DIM;
    const float* p2 = protos + (size_t)i2 * DIM;
    float* orow = out + (size_t)(wr0 + r) * DIM;
#pragma unroll
    for (int h = 0; h < 2; ++h) {
      const int col = h * 256 + l * 4;
      const float4 x = *(const float4*)(p0 + col);
      const float4 y = *(const float4*)(p1 + col);
      const float4 z = *(const float4*)(p2 + col);
      float4 res;
      res.x = wi.x * x.x + wi.y * y.x + wi.z * z.x;
      res.y = wi.x * x.y + wi.y * y.y + wi.z * z.y;
      res.z = wi.x * x.z + wi.y * y.z + wi.z * z.z;
      res.w = wi.x * x.w + wi.y * y.w + wi.z * z.w;
      *(float4*)(orow + col) = res;
    }
  }
}

// ---------------------------------------------------------------------------
// Kernel 4: fp64 refine of compacted near-tie rows. One wave per row.
// ---------------------------------------------------------------------------
__global__ __launch_bounds__(256) void refine_kernel(
    const float* __restrict__ query, const float* __restrict__ protos,
    const float* __restrict__ ptw, const double* __restrict__ inv64,
    const int* __restrict__ cnt, const int* __restrict__ list,
    float* __restrict__ out) {
  const int n = min(*cnt, LISTCAP);
  const int lane = threadIdx.x & 63;
  const int gw = blockIdx.x * 4 + (threadIdx.x >> 6);

  for (int i = gw; i < n; i += RFB * 4) {
    const int row = list[i];
    const float* q = query + (size_t)row * DIM;
    double a0 = 0.0, a1 = 0.0, a2 = 0.0, a3 = 0.0;
    float qs = 0.f;
#pragma unroll 4
    for (int k = 0; k < DIM; k += 4) {
      const float4 qv = *(const float4*)(q + k);
      a0 = fma((double)qv.x, (double)ptw[(size_t)(k + 0) * NP + lane], a0);
      a1 = fma((double)qv.y, (double)ptw[(size_t)(k + 1) * NP + lane], a1);
      a2 = fma((double)qv.z, (double)ptw[(size_t)(k + 2) * NP + lane], a2);
      a3 = fma((double)qv.w, (double)ptw[(size_t)(k + 3) * NP + lane], a3);
      qs += qv.x * qv.x + qv.y * qv.y + qv.z * qv.z + qv.w * qv.w;
    }
    const double sim = (a0 + a1 + a2 + a3) * inv64[lane];

    double b0 = sim, b1 = -1e300, b2 = -1e300;
    int k0 = lane, k1 = 0, k2 = 0;
#pragma unroll
    for (int m = 1; m <= 32; m <<= 1) {
      const double p0 = __shfl_xor(b0, m), p1 = __shfl_xor(b1, m),
                   p2 = __shfl_xor(b2, m);
      const int q0 = __shfl_xor(k0, m), q1 = __shfl_xor(k1, m),
                q2 = __shfl_xor(k2, m);
      ins3d(p0, q0, b0, b1, b2, k0, k1, k2);
      ins3d(p1, q1, b0, b1, b2, k0, k1, k2);
      ins3d(p2, q2, b0, b1, b2, k0, k1, k2);
    }
    const double qi = 1.0 / fmax(sqrt((double)qs), 1e-12);
    const double s0 = b0 * qi, s1 = b1 * qi, s2 = b2 * qi;
    const double e1 = exp(s1 - s0), e2 = exp(s2 - s0);
    const double inv = 1.0 / (1.0 + e1 + e2);
    const double w0 = inv, w1 = e1 * inv, w2 = e2 * inv;
    const float* p0r = protos + (size_t)k0 * DIM;
    const float* p1r = protos + (size_t)k1 * DIM;
    const float* p2r = protos + (size_t)k2 * DIM;
#pragma unroll
    for (int u = 0; u < 2; ++u) {
      const int col = u * 256 + lane * 4;
      const float4 x = *(const float4*)(p0r + col);
      const float4 y = *(const float4*)(p1r + col);
      const float4 z = *(const float4*)(p2r + col);
      float4 res;
      res.x = (float)(w0 * x.x + w1 * y.x + w2 * z.x);
      res.y = (float)(w0 * x.y + w1 * y.y + w2 * z.y);
      res.z = (float)(w0 * x.z + w1 * y.z + w2 * z.z);
      res.w = (float)(w0 * x.w + w1 * y.w + w2 * z.w);
      *(float4*)(out + (size_t)row * DIM + col) = res;
    }
  }
}

extern "C" void kernel_launch(void* const* d_in, const int* in_sizes, int n_in,
                              void* d_out, int out_size, void* d_ws, size_t ws_size,
                              hipStream_t stream) {
  const float* query = (const float*)d_in[0];
  const float* protos = (const float*)d_in[1];
  float* out = (float*)d_out;
  float* ptw = (float*)((char*)d_ws + WS_PTW);
  unsigned short* bhi = (unsigned short*)((char*)d_ws + WS_BHI);
  unsigned short* blo = (unsigned short*)((char*)d_ws + WS_BLO);
  double* inv64 = (double*)((char*)d_ws + WS_INV64);
  int* cnt = (int*)((char*)d_ws + WS_CNT);
  int* list = (int*)((char*)d_ws + WS_LIST);

  const int nrows = in_sizes[0] / DIM;

  hipLaunchKernelGGL(prep_kernel, dim3(16), dim3(256), 0, stream,
                     protos, ptw, inv64, cnt);
  hipLaunchKernelGGL(prep_frag_kernel, dim3(64), dim3(64), 0, stream,
                     protos, inv64, bhi, blo);
  hipLaunchKernelGGL(sim_kernel, dim3(nrows / RPB), dim3(256), 0, stream,
                     query, protos, bhi, blo, out, cnt, list);
  hipLaunchKernelGGL(refine_kernel, dim3(RFB), dim3(256), 0, stream,
                     query, protos, ptw, inv64, cnt, list, out);
}